// Round 1
// baseline (101.633 us; speedup 1.0000x reference)
//
#include <hip/hip_runtime.h>

typedef __attribute__((ext_vector_type(4))) float  f32x4;
typedef __attribute__((ext_vector_type(8))) __bf16 bf16x8;
typedef __attribute__((ext_vector_type(4))) __bf16 bf16x4;

#define MFMA16(a, b, c) __builtin_amdgcn_mfma_f32_16x16x32_bf16((a), (b), (c), 0, 0, 0)

// One block per (b,h): bs=2048, h=8, dh=32, qsl=sl=64.
__global__ __launch_bounds__(256, 4)
void mha_fused(const float* __restrict__ qg, const float* __restrict__ kg,
               const float* __restrict__ vg, const unsigned char* __restrict__ maskg,
               const float* __restrict__ gammag, const float* __restrict__ biasg,
               float* __restrict__ outg)
{
    const int bh = blockIdx.x;
    const int b  = bh >> 3;
    const int h  = bh & 7;
    const int t  = threadIdx.x;

    // Strides: 40 bf16 = 80 B = 5*16 B (bank-group step 5, coprime 8 -> conflict-free b128)
    //          72 bf16 = 144 B = 9*16 B (step 9 -> step 1 mod 8 -> conflict-free b128)
    __shared__ __bf16 sQh[64][40];           // Q^T hi  [i][d]
    __shared__ __bf16 sQl[64][40];           // Q^T lo
    __shared__ __bf16 sKh[64][40];           // K^T hi  [j][d]
    __shared__ __bf16 sKl[64][40];           // K^T lo
    __shared__ __bf16 sV [32][72];           // V bf16  [d][j]
    __shared__ __bf16 sW [64][72];           // W bf16  [i][j]
    __shared__ unsigned char sM[64][80];     // mask    [i][j]

    const float* qb = qg + (size_t)bh * 2048;
    const float* kb = kg + (size_t)bh * 2048;
    const float* vb = vg + (size_t)bh * 2048;
    const unsigned char* mb = maskg + (size_t)b * 4096;  // mask broadcast over h
    float* ob = outg + (size_t)bh * 2048;

    // ---- stage Q,K transposed to [i][d] as split-bf16 (hi + residual lo) ----
    {
        const int i = t & 63;
        #pragma unroll
        for (int g = 0; g < 2; ++g) {
            const int d0 = ((t >> 6) + 4 * g) * 4;
            float a0 = qb[(d0 + 0) * 64 + i];
            float a1 = qb[(d0 + 1) * 64 + i];
            float a2 = qb[(d0 + 2) * 64 + i];
            float a3 = qb[(d0 + 3) * 64 + i];
            __bf16 h0 = (__bf16)a0, h1 = (__bf16)a1, h2 = (__bf16)a2, h3 = (__bf16)a3;
            *(bf16x4*)&sQh[i][d0] = (bf16x4){h0, h1, h2, h3};
            *(bf16x4*)&sQl[i][d0] = (bf16x4){(__bf16)(a0 - (float)h0), (__bf16)(a1 - (float)h1),
                                             (__bf16)(a2 - (float)h2), (__bf16)(a3 - (float)h3)};
            a0 = kb[(d0 + 0) * 64 + i];
            a1 = kb[(d0 + 1) * 64 + i];
            a2 = kb[(d0 + 2) * 64 + i];
            a3 = kb[(d0 + 3) * 64 + i];
            h0 = (__bf16)a0; h1 = (__bf16)a1; h2 = (__bf16)a2; h3 = (__bf16)a3;
            *(bf16x4*)&sKh[i][d0] = (bf16x4){h0, h1, h2, h3};
            *(bf16x4*)&sKl[i][d0] = (bf16x4){(__bf16)(a0 - (float)h0), (__bf16)(a1 - (float)h1),
                                             (__bf16)(a2 - (float)h2), (__bf16)(a3 - (float)h3)};
        }
    }
    // ---- stage V as bf16, natural [d][j] ----
    {
        const int d = t >> 3, j0 = (t & 7) * 8;
        f32x4 x0 = *(const f32x4*)&vb[d * 64 + j0];
        f32x4 x1 = *(const f32x4*)&vb[d * 64 + j0 + 4];
        bf16x8 vv = {(__bf16)x0[0], (__bf16)x0[1], (__bf16)x0[2], (__bf16)x0[3],
                     (__bf16)x1[0], (__bf16)x1[1], (__bf16)x1[2], (__bf16)x1[3]};
        *(bf16x8*)&sV[d][j0] = vv;
    }
    // ---- stage mask ----
    {
        const int i = t >> 2, j0 = (t & 3) * 16;
        uint4 m4 = *(const uint4*)&mb[i * 64 + j0];
        *(uint4*)&sM[i][j0] = m4;
    }
    __syncthreads();

    const int w  = t >> 6;        // wave id: owns query columns i = w*16 .. w*16+15
    const int li = t & 15;
    const int hi = (t >> 4) & 3;
    const int i  = w * 16 + li;

    // ---- S^T[j][i] = sum_d K^T[j][d] * Q[d][i]  (split-bf16, 3 MFMAs per tile) ----
    bf16x8 qh = *(bf16x8*)&sQh[i][hi * 8];
    bf16x8 ql = *(bf16x8*)&sQl[i][hi * 8];
    f32x4 acc[4];
    #pragma unroll
    for (int jt = 0; jt < 4; ++jt) {
        bf16x8 ah = *(bf16x8*)&sKh[jt * 16 + li][hi * 8];
        bf16x8 al = *(bf16x8*)&sKl[jt * 16 + li][hi * 8];
        f32x4 c = {0.f, 0.f, 0.f, 0.f};
        c = MFMA16(al, qh, c);   // lo*hi
        c = MFMA16(ah, ql, c);   // hi*lo
        c = MFMA16(ah, qh, c);   // hi*hi
        acc[jt] = c;
    }

    // ---- per-lane: 16 scores (j = jt*16 + hi*4 + r) for fixed query i ----
    const float ga = gammag[h], be = biasg[h];
    float s[16];
    #pragma unroll
    for (int jt = 0; jt < 4; ++jt) {
        const unsigned int mw = *(const unsigned int*)&sM[i][jt * 16 + hi * 4];
        #pragma unroll
        for (int r = 0; r < 4; ++r) {
            float x = acc[jt][r] * ga + be;
            if ((mw >> (8 * r)) & 0xffu) x = -1.0e9f;
            s[jt * 4 + r] = x;
        }
    }
    // row max / sum across the 4 hi-groups holding the same i
    float m = s[0];
    #pragma unroll
    for (int e = 1; e < 16; ++e) m = fmaxf(m, s[e]);
    m = fmaxf(m, __shfl_xor(m, 16));
    m = fmaxf(m, __shfl_xor(m, 32));
    float p[16], sum = 0.f;
    #pragma unroll
    for (int e = 0; e < 16; ++e) { p[e] = __expf(s[e] - m); sum += p[e]; }
    sum += __shfl_xor(sum, 16);
    sum += __shfl_xor(sum, 32);
    const float inv = 1.0f / sum;

    // ---- gate: w = softmax * sigmoid; write bf16 W[i][j] ----
    #pragma unroll
    for (int jt = 0; jt < 4; ++jt) {
        __bf16 wv0, wv1, wv2, wv3;
        {
            const int e = jt * 4 + 0; float g = 1.0f / (1.0f + __expf(-s[e])); wv0 = (__bf16)(p[e] * inv * g);
        }
        {
            const int e = jt * 4 + 1; float g = 1.0f / (1.0f + __expf(-s[e])); wv1 = (__bf16)(p[e] * inv * g);
        }
        {
            const int e = jt * 4 + 2; float g = 1.0f / (1.0f + __expf(-s[e])); wv2 = (__bf16)(p[e] * inv * g);
        }
        {
            const int e = jt * 4 + 3; float g = 1.0f / (1.0f + __expf(-s[e])); wv3 = (__bf16)(p[e] * inv * g);
        }
        *(bf16x4*)&sW[i][jt * 16 + hi * 4] = (bf16x4){wv0, wv1, wv2, wv3};
    }

    // ---- out[d][i] = sum_j V[d][j] * W^T[j][i]  (wave-local W rows; no barrier) ----
    f32x4 o0 = {0.f, 0.f, 0.f, 0.f};
    f32x4 o1 = {0.f, 0.f, 0.f, 0.f};
    #pragma unroll
    for (int kt = 0; kt < 2; ++kt) {
        bf16x8 wb = *(bf16x8*)&sW[i][kt * 32 + hi * 8];
        bf16x8 va = *(bf16x8*)&sV[li][kt * 32 + hi * 8];
        bf16x8 vc = *(bf16x8*)&sV[16 + li][kt * 32 + hi * 8];
        o0 = MFMA16(va, wb, o0);
        o1 = MFMA16(vc, wb, o1);
    }
    #pragma unroll
    for (int r = 0; r < 4; ++r) {
        ob[(hi * 4 + r) * 64 + i]      = o0[r];
        ob[(16 + hi * 4 + r) * 64 + i] = o1[r];
    }
}

extern "C" void kernel_launch(void* const* d_in, const int* in_sizes, int n_in,
                              void* d_out, int out_size, void* d_ws, size_t ws_size,
                              hipStream_t stream)
{
    const float* q = (const float*)d_in[0];
    const float* k = (const float*)d_in[1];
    const float* v = (const float*)d_in[2];
    const unsigned char* mask = (const unsigned char*)d_in[3];
    const float* gamma = (const float*)d_in[4];
    const float* bias  = (const float*)d_in[5];
    float* out = (float*)d_out;

    const int num_bh = in_sizes[0] / 2048;   // bs*h = 16384
    dim3 grid(num_bh), block(256);
    hipLaunchKernelGGL(mha_fused, grid, block, 0, stream,
                       q, k, v, mask, gamma, bias, out);
}